// Round 8
// baseline (342.227 us; speedup 1.0000x reference)
//
#include <hip/hip_runtime.h>

#define N_NODES 100000
#define N_EDGES 3200000
#define NUM_FEATURES 128
#define DIM 10
#define NUM_GRAPHS 64

#define BSHIFT 8                             // 256 nodes per bucket
#define BSIZE (1 << BSHIFT)
#define NB ((N_NODES + BSIZE - 1) / BSIZE)   // 391 buckets
#define CHUNKS 2                             // chunks per bucket (spmm1/pass2)
#define EPB 12500                            // edges per hist/place block
#define EBLOCKS 256                          // 256 * 12500 = 3.2M exact
#define TILE (BSIZE * DIM)                   // 2560 floats per bucket tile
#define HSTRIDE 16                           // padded row stride: 64B-aligned rows
#define CAP 4608                             // max edges per spmm1 chunk (~+11 sigma)
#define NCHUNK (NB * CHUNKS)                 // 782
#define ACC_STRIDE 11

// ---------------------------------------------------------------------------
// h1 = features @ W1, rows padded to stride 16 (one 64B line per row)
// ---------------------------------------------------------------------------
__global__ __launch_bounds__(256) void k_gemm_w1(const float* __restrict__ feat,
                                                 const float* __restrict__ W1,
                                                 float* __restrict__ h1) {
    int gid  = blockIdx.x * blockDim.x + threadIdx.x;
    int node = gid >> 5;
    int lane = gid & 31;
    if (node >= N_NODES) return;

    float w[4][DIM];
#pragma unroll
    for (int j = 0; j < 4; ++j)
#pragma unroll
        for (int k = 0; k < DIM; ++k)
            w[j][k] = W1[(lane * 4 + j) * DIM + k];

    const float4 f = *reinterpret_cast<const float4*>(feat + (size_t)node * NUM_FEATURES + lane * 4);
    float fv[4] = {f.x, f.y, f.z, f.w};

    float acc[DIM];
#pragma unroll
    for (int k = 0; k < DIM; ++k) acc[k] = 0.f;
#pragma unroll
    for (int j = 0; j < 4; ++j)
#pragma unroll
        for (int k = 0; k < DIM; ++k)
            acc[k] += fv[j] * w[j][k];

#pragma unroll
    for (int off = 16; off > 0; off >>= 1)
#pragma unroll
        for (int k = 0; k < DIM; ++k)
            acc[k] += __shfl_xor(acc[k], off);

    if (lane == 0) {
#pragma unroll
        for (int k = 0; k < DIM; ++k) h1[(size_t)node * HSTRIDE + k] = acc[k];
    }
}

// ---------------------------------------------------------------------------
// Graph boundaries from sorted gids
// ---------------------------------------------------------------------------
__global__ __launch_bounds__(256) void k_bounds(const int* __restrict__ gids,
                                                int* __restrict__ bound) {
    int n = blockIdx.x * blockDim.x + threadIdx.x;
    if (n >= N_NODES) return;
    int g  = gids[n];
    int gp = n ? gids[n - 1] : -1;
    for (int v = gp + 1; v <= g; ++v) bound[v] = n;
    if (n == N_NODES - 1)
        for (int v = g + 1; v <= NUM_GRAPHS; ++v) bound[v] = N_NODES;
}

// ---------------------------------------------------------------------------
// Per-block dst-bucket histogram -> H[block][bin]  (1 LDS atomic / edge)
// ---------------------------------------------------------------------------
__global__ __launch_bounds__(512) void k_hist(const int* __restrict__ dst,
                                              int* __restrict__ H) {
    __shared__ int hd[NB];
    for (int t = threadIdx.x; t < NB; t += 512) hd[t] = 0;
    __syncthreads();
    int base = blockIdx.x * EPB;
    int end  = min(base + EPB, N_EDGES);
    for (int i = base + threadIdx.x; i < end; i += 512)
        atomicAdd(&hd[dst[i] >> BSHIFT], 1);
    __syncthreads();
    int* Hrow = H + (size_t)blockIdx.x * NB;
    for (int t = threadIdx.x; t < NB; t += 512) Hrow[t] = hd[t];
}

// ---------------------------------------------------------------------------
// Convert H to per-(block,bin) start offsets in place; emit bstart[NB+1].
// Thread t owns bin t.
// ---------------------------------------------------------------------------
__global__ __launch_bounds__(512) void k_scan(int* __restrict__ H,
                                              int* __restrict__ bstart) {
    __shared__ int ld[512];
    int t = threadIdx.x;
    int tot = 0;
    if (t < NB)
        for (int bk = 0; bk < EBLOCKS; ++bk) tot += H[(size_t)bk * NB + t];
    ld[t] = (t < NB) ? tot : 0;
    __syncthreads();
    for (int off = 1; off < 512; off <<= 1) {
        int v = (t >= off) ? ld[t - off] : 0;
        __syncthreads();
        ld[t] += v;
        __syncthreads();
    }
    int base = t ? ld[t - 1] : 0;
    if (t < NB) bstart[t] = base;
    if (t == NB - 1) bstart[NB] = ld[t];
    if (t < NB) {
        int run = base;
        for (int bk = 0; bk < EBLOCKS; ++bk) {
            int x = H[(size_t)bk * NB + t];
            H[(size_t)bk * NB + t] = run;
            run += x;
        }
    }
}

// ---------------------------------------------------------------------------
// Placement with precomputed cursors: 1 LDS atomic / edge.
// pk[pos] = (dst&255)<<17 | src   (dst-bucket-sorted)
// ---------------------------------------------------------------------------
__global__ __launch_bounds__(512) void k_bplace(const int* __restrict__ src,
                                                const int* __restrict__ dst,
                                                const int* __restrict__ OFF,
                                                int* __restrict__ pk) {
    __shared__ int cur[NB];
    const int* off = OFF + (size_t)blockIdx.x * NB;
    for (int t = threadIdx.x; t < NB; t += 512) cur[t] = off[t];
    __syncthreads();
    int base = blockIdx.x * EPB;
    int end  = min(base + EPB, N_EDGES);
    for (int i = base + threadIdx.x; i < end; i += 512) {
        int d = dst[i];
        int s = src[i];
        int pos = atomicAdd(&cur[d >> BSHIFT], 1);
        pk[pos] = ((d & (BSIZE - 1)) << 17) | s;
    }
}

// ---------------------------------------------------------------------------
// Pass 1 SpMM: in-block counting sort to exact dst-loc (2 LDS atomics/edge),
// then exclusive-owner segmented gather, register acc, non-atomic writes.
// ---------------------------------------------------------------------------
__global__ __launch_bounds__(512) void k_spmm1(const float* __restrict__ h,
                                               const int* __restrict__ bstart,
                                               const int* __restrict__ pk,
                                               float* __restrict__ part) {
    __shared__ int eh[CAP];
    __shared__ int srt[CAP];
    __shared__ int hist[BSIZE];
    __shared__ int cur[BSIZE];

    int b     = blockIdx.x / CHUNKS;
    int chunk = blockIdx.x % CHUNKS;
    int s0  = bstart[b];
    int len = bstart[b + 1] - s0;
    int c0  = s0 + (len * chunk) / CHUNKS;
    int c1  = s0 + (len * (chunk + 1)) / CHUNKS;
    int n   = c1 - c0;
    int nc  = min(n, CAP);

    for (int t = threadIdx.x; t < BSIZE; t += 512) hist[t] = 0;
    __syncthreads();

    for (int i = threadIdx.x; i < nc; i += 512) {
        int p = pk[c0 + i];
        eh[i] = p;
        atomicAdd(&hist[p >> 17], 1);
    }
    __syncthreads();

    if (threadIdx.x < 64) {
        int l = threadIdx.x;
        int carry = 0;
#pragma unroll
        for (int j = 0; j < 4; ++j) {
            int x = hist[j * 64 + l];
            int v = x;
#pragma unroll
            for (int off = 1; off < 64; off <<= 1) {
                int t2 = __shfl_up(v, off);
                if (l >= off) v += t2;
            }
            cur[j * 64 + l] = carry + v - x;
            carry += __shfl(v, 63);
        }
    }
    __syncthreads();

    for (int i = threadIdx.x; i < nc; i += 512) {
        int p = eh[i];
        int pos = atomicAdd(&cur[p >> 17], 1);
        srt[pos] = p;
    }
    __syncthreads();

    int wave = threadIdx.x >> 6;
    int lane = threadIdx.x & 63;
    int grp  = lane / 10;
    int k    = lane - grp * 10;
    float* pb = part + (size_t)blockIdx.x * TILE;

    if (grp < 6) {
        int g48 = wave * 6 + grp;
        for (int loc = g48; loc < BSIZE; loc += 48) {
            int e0 = loc ? cur[loc - 1] : 0;
            int e1 = cur[loc];
            float a0 = 0.f, a1 = 0.f, a2 = 0.f, a3 = 0.f;
            int e = e0;
            for (; e + 3 < e1; e += 4) {
                int p0 = srt[e], p1 = srt[e + 1], p2 = srt[e + 2], p3 = srt[e + 3];
                a0 += h[(size_t)(p0 & 0x1FFFF) * HSTRIDE + k];
                a1 += h[(size_t)(p1 & 0x1FFFF) * HSTRIDE + k];
                a2 += h[(size_t)(p2 & 0x1FFFF) * HSTRIDE + k];
                a3 += h[(size_t)(p3 & 0x1FFFF) * HSTRIDE + k];
            }
            for (; e < e1; ++e)
                a0 += h[(size_t)(srt[e] & 0x1FFFF) * HSTRIDE + k];
            pb[loc * DIM + k] = (a0 + a1) + (a2 + a3);
        }
    }
    __syncthreads();

    // overflow fallback (statistically never; correctness guard)
    for (int i = CAP + threadIdx.x; i < n; i += 512) {
        int p = pk[c0 + i];
        int loc = p >> 17, s = p & 0x1FFFF;
#pragma unroll
        for (int kk = 0; kk < DIM; ++kk)
            atomicAdd(&pb[loc * DIM + kk], h[(size_t)s * HSTRIDE + kk]);
    }
}

// merge CHUNKS partials + fused relu -> r (stride 16, 64B-aligned rows)
__global__ __launch_bounds__(256) void k_merge_relu(const float* __restrict__ part,
                                                    float* __restrict__ r) {
    int b     = blockIdx.x;
    int nbase = b << BSHIFT;
    const float* p0 = part + (size_t)(b * CHUNKS) * TILE;
    for (int t = threadIdx.x; t < TILE; t += 256) {
        float s = 0.f;
#pragma unroll
        for (int c = 0; c < CHUNKS; ++c) s += p0[c * TILE + t];
        int node = nbase + t / DIM;
        if (node < N_NODES) r[(size_t)node * HSTRIDE + t % DIM] = fmaxf(s, 0.f);
    }
}

// ---------------------------------------------------------------------------
// Pass 2 v3: walk the dst-sorted pk directly. gid is monotone within the
// walk -> per-slot running register sum, LDS flush only on gid change.
// Zero per-edge atomics; 4-deep gather pipeline.
// ---------------------------------------------------------------------------
__global__ __launch_bounds__(512) void k_pass2(const float* __restrict__ r,
                                               const int* __restrict__ bstart,
                                               const int* __restrict__ pk,
                                               const int* __restrict__ bound,
                                               float* __restrict__ part2) {
    __shared__ float acc[NUM_GRAPHS * ACC_STRIDE];
    __shared__ unsigned char locgid[BSIZE];
    __shared__ int bnd[NUM_GRAPHS + 1];

    int b     = blockIdx.x / CHUNKS;
    int chunk = blockIdx.x % CHUNKS;
    int nbase = b << BSHIFT;

    if (threadIdx.x < NUM_GRAPHS + 1) bnd[threadIdx.x] = bound[threadIdx.x];
    for (int t = threadIdx.x; t < NUM_GRAPHS * ACC_STRIDE; t += 512) acc[t] = 0.f;
    __syncthreads();
    if (threadIdx.x < BSIZE) {
        int node = min(nbase + threadIdx.x, N_NODES - 1);
        int lo = 0, hi = NUM_GRAPHS - 1;
#pragma unroll
        for (int it = 0; it < 6; ++it) {
            int mid = (lo + hi + 1) >> 1;
            if (bnd[mid] <= node) lo = mid; else hi = mid - 1;
        }
        locgid[threadIdx.x] = (unsigned char)lo;
    }
    __syncthreads();

    int s0  = bstart[b];
    int len = bstart[b + 1] - s0;
    int c0  = s0 + (len * chunk) / CHUNKS;
    int c1  = s0 + (len * (chunk + 1)) / CHUNKS;

    int wave = threadIdx.x >> 6;
    int lane = threadIdx.x & 63;
    int slot = lane / 10;
    int k    = lane - slot * 10;

    if (slot < 6) {
        const int STR = 48;
        float sum = 0.f;
        int cur = -1;
        int e = c0 + wave * 6 + slot;
#define P2_STEP(pp, vv)                                              \
        {                                                            \
            int g_ = locgid[(pp) >> 17];                             \
            if (g_ != cur) {                                         \
                if (cur >= 0) atomicAdd(&acc[cur * ACC_STRIDE + k], sum); \
                sum = 0.f; cur = g_;                                 \
            }                                                        \
            sum += (vv);                                             \
        }
        for (; e + 3 * STR < c1; e += 4 * STR) {
            int p0 = pk[e], p1 = pk[e + STR], p2 = pk[e + 2 * STR], p3 = pk[e + 3 * STR];
            float v0 = r[(size_t)(p0 & 0x1FFFF) * HSTRIDE + k];
            float v1 = r[(size_t)(p1 & 0x1FFFF) * HSTRIDE + k];
            float v2 = r[(size_t)(p2 & 0x1FFFF) * HSTRIDE + k];
            float v3 = r[(size_t)(p3 & 0x1FFFF) * HSTRIDE + k];
            P2_STEP(p0, v0) P2_STEP(p1, v1) P2_STEP(p2, v2) P2_STEP(p3, v3)
        }
        for (; e < c1; e += STR) {
            int p = pk[e];
            float v = r[(size_t)(p & 0x1FFFF) * HSTRIDE + k];
            P2_STEP(p, v)
        }
        if (cur >= 0) atomicAdd(&acc[cur * ACC_STRIDE + k], sum);
#undef P2_STEP
    }
    __syncthreads();

    float* po = part2 + (size_t)blockIdx.x * (NUM_GRAPHS * DIM);
    for (int t = threadIdx.x; t < NUM_GRAPHS * DIM; t += 512)
        po[t] = acc[(t / DIM) * ACC_STRIDE + t % DIM];
}

// sum chunk partials -> sums (global atomics, 6400 total; sums pre-zeroed)
__global__ __launch_bounds__(640) void k_sums(const float* __restrict__ part2,
                                              float* __restrict__ sums) {
    int t  = threadIdx.x;                 // 0..639 = g*10+k
    int b0 = blockIdx.x * 79;
    int b1 = min(b0 + 79, NCHUNK);
    float s = 0.f;
    for (int c = b0; c < b1; ++c) s += part2[(size_t)c * (NUM_GRAPHS * DIM) + t];
    atomicAdd(&sums[t], s);
}

// out[g] = sigmoid(((sums[g]/max(cnt,1)) @ W2) @ W3)
__global__ void k_final(const float* __restrict__ sums, const int* __restrict__ bound,
                        const float* __restrict__ W2, const float* __restrict__ W3,
                        float* __restrict__ out) {
    int g = threadIdx.x;
    if (g >= NUM_GRAPHS) return;
    float c = fmaxf((float)(bound[g + 1] - bound[g]), 1.f);
    float p[DIM];
#pragma unroll
    for (int k = 0; k < DIM; ++k) p[k] = sums[g * DIM + k] / c;
    float z = 0.f;
#pragma unroll
    for (int j = 0; j < DIM; ++j) {
        float t = 0.f;
#pragma unroll
        for (int k = 0; k < DIM; ++k) t += p[k] * W2[k * DIM + j];
        z += t * W3[j];
    }
    out[g] = 1.f / (1.f + expf(-z));
}

// ---------------------------------------------------------------------------
// Workspace (bytes):
//   h1     [0,         6400000)   100k x 16 f32
//   pk     [6400000,  19200000)   3.2M int, dst-bucket-sorted (used by BOTH passes)
//   r      [19200000, 25600000)   100k x 16 f32 (relu(agg1))
//   part   [25600000, 33607680)   782 x 2560 f32; part2 (782x640) aliases
//   H/OFF  [33607680, 34008064)   256 x 391 int
//   bstart [34008064, 34009632)   392 int
//   bound  [34009632, 34009892)   65 int
//   sums   [34009892, 34012452)   640 f32   <- zeroed
// ---------------------------------------------------------------------------
extern "C" void kernel_launch(void* const* d_in, const int* in_sizes, int n_in,
                              void* d_out, int out_size, void* d_ws, size_t ws_size,
                              hipStream_t stream) {
    const float* feat = (const float*)d_in[0];
    const float* W1   = (const float*)d_in[1];
    const float* W2   = (const float*)d_in[2];
    const float* W3   = (const float*)d_in[3];
    const int*   src  = (const int*)d_in[4];
    const int*   dst  = (const int*)d_in[5];
    const int*   gids = (const int*)d_in[6];
    float*       out  = (float*)d_out;

    char* ws = (char*)d_ws;
    float* h1     = (float*)(ws);
    int*   pk     = (int*)(ws + 6400000);
    float* r      = (float*)(ws + 19200000);
    float* part   = (float*)(ws + 25600000);
    float* part2  = (float*)(ws + 25600000);   // aliases part (dead after merge)
    int*   H      = (int*)(ws + 33607680);
    int*   bstart = (int*)(ws + 34008064);
    int*   bound  = (int*)(ws + 34009632);
    float* sums   = (float*)(ws + 34009892);

    hipMemsetAsync(sums, 0, 2560, stream);

    k_gemm_w1<<<(N_NODES * 32 + 255) / 256, 256, 0, stream>>>(feat, W1, h1);
    k_bounds <<<(N_NODES + 255) / 256, 256, 0, stream>>>(gids, bound);
    k_hist   <<<EBLOCKS, 512, 0, stream>>>(dst, H);
    k_scan   <<<1, 512, 0, stream>>>(H, bstart);
    k_bplace <<<EBLOCKS, 512, 0, stream>>>(src, dst, H, pk);

    k_spmm1     <<<NCHUNK, 512, 0, stream>>>(h1, bstart, pk, part);
    k_merge_relu<<<NB, 256, 0, stream>>>(part, r);
    k_pass2     <<<NCHUNK, 512, 0, stream>>>(r, bstart, pk, bound, part2);
    k_sums      <<<(NCHUNK + 78) / 79, 640, 0, stream>>>(part2, sums);

    k_final<<<1, 64, 0, stream>>>(sums, bound, W2, W3, out);
}

// Round 10
// 330.314 us; speedup vs baseline: 1.0361x; 1.0361x over previous
//
#include <hip/hip_runtime.h>
#include <hip/hip_fp16.h>

#define N_NODES 100000
#define N_EDGES 3200000
#define NUM_FEATURES 128
#define DIM 10
#define NUM_GRAPHS 64

#define BSHIFT 8                             // 256 nodes per bucket
#define BSIZE (1 << BSHIFT)
#define NB ((N_NODES + BSIZE - 1) / BSIZE)   // 391 buckets
#define CHUNKS 2                             // chunks per bucket (spmm1/pass2)
#define EPB 12500                            // edges per hist/place block
#define EBLOCKS 256                          // 256 * 12500 = 3.2M exact
#define TILE (BSIZE * DIM)                   // 2560 floats per bucket tile
#define CAP 4608                             // max edges per spmm1 chunk (~+11 sigma)
#define NCHUNK (NB * CHUNKS)                 // 782
#define ACC_STRIDE 11

// ---------------------------------------------------------------------------
// h1 = features @ W1 -> fp16, compact stride 10 (2 MB total: L2-resident)
// ---------------------------------------------------------------------------
__global__ __launch_bounds__(256) void k_gemm_w1(const float* __restrict__ feat,
                                                 const float* __restrict__ W1,
                                                 __half* __restrict__ h1) {
    int gid  = blockIdx.x * blockDim.x + threadIdx.x;
    int node = gid >> 5;
    int lane = gid & 31;
    if (node >= N_NODES) return;

    float w[4][DIM];
#pragma unroll
    for (int j = 0; j < 4; ++j)
#pragma unroll
        for (int k = 0; k < DIM; ++k)
            w[j][k] = W1[(lane * 4 + j) * DIM + k];

    const float4 f = *reinterpret_cast<const float4*>(feat + (size_t)node * NUM_FEATURES + lane * 4);
    float fv[4] = {f.x, f.y, f.z, f.w};

    float acc[DIM];
#pragma unroll
    for (int k = 0; k < DIM; ++k) acc[k] = 0.f;
#pragma unroll
    for (int j = 0; j < 4; ++j)
#pragma unroll
        for (int k = 0; k < DIM; ++k)
            acc[k] += fv[j] * w[j][k];

#pragma unroll
    for (int off = 16; off > 0; off >>= 1)
#pragma unroll
        for (int k = 0; k < DIM; ++k)
            acc[k] += __shfl_xor(acc[k], off);

    if (lane == 0) {
        __half2* o = (__half2*)h1;
#pragma unroll
        for (int j = 0; j < 5; ++j)
            o[(size_t)node * 5 + j] = __floats2half2_rn(acc[2 * j], acc[2 * j + 1]);
    }
}

// ---------------------------------------------------------------------------
// Graph boundaries from sorted gids
// ---------------------------------------------------------------------------
__global__ __launch_bounds__(256) void k_bounds(const int* __restrict__ gids,
                                                int* __restrict__ bound) {
    int n = blockIdx.x * blockDim.x + threadIdx.x;
    if (n >= N_NODES) return;
    int g  = gids[n];
    int gp = n ? gids[n - 1] : -1;
    for (int v = gp + 1; v <= g; ++v) bound[v] = n;
    if (n == N_NODES - 1)
        for (int v = g + 1; v <= NUM_GRAPHS; ++v) bound[v] = N_NODES;
}

// ---------------------------------------------------------------------------
// Per-block dst-bucket histogram -> H[block][bin]  (1 LDS atomic / edge)
// ---------------------------------------------------------------------------
__global__ __launch_bounds__(512) void k_hist(const int* __restrict__ dst,
                                              int* __restrict__ H) {
    __shared__ int hd[NB];
    for (int t = threadIdx.x; t < NB; t += 512) hd[t] = 0;
    __syncthreads();
    int base = blockIdx.x * EPB;
    int end  = min(base + EPB, N_EDGES);
    for (int i = base + threadIdx.x; i < end; i += 512)
        atomicAdd(&hd[dst[i] >> BSHIFT], 1);
    __syncthreads();
    int* Hrow = H + (size_t)blockIdx.x * NB;
    for (int t = threadIdx.x; t < NB; t += 512) Hrow[t] = hd[t];
}

// ---------------------------------------------------------------------------
// Convert H to per-(block,bin) start offsets in place; emit bstart[NB+1].
// ---------------------------------------------------------------------------
__global__ __launch_bounds__(512) void k_scan(int* __restrict__ H,
                                              int* __restrict__ bstart) {
    __shared__ int ld[512];
    int t = threadIdx.x;
    int tot = 0;
    if (t < NB)
        for (int bk = 0; bk < EBLOCKS; ++bk) tot += H[(size_t)bk * NB + t];
    ld[t] = (t < NB) ? tot : 0;
    __syncthreads();
    for (int off = 1; off < 512; off <<= 1) {
        int v = (t >= off) ? ld[t - off] : 0;
        __syncthreads();
        ld[t] += v;
        __syncthreads();
    }
    int base = t ? ld[t - 1] : 0;
    if (t < NB) bstart[t] = base;
    if (t == NB - 1) bstart[NB] = ld[t];
    if (t < NB) {
        int run = base;
        for (int bk = 0; bk < EBLOCKS; ++bk) {
            int x = H[(size_t)bk * NB + t];
            H[(size_t)bk * NB + t] = run;
            run += x;
        }
    }
}

// ---------------------------------------------------------------------------
// Placement with precomputed cursors: 1 LDS atomic / edge.
// pk[pos] = (dst&255)<<17 | src
// ---------------------------------------------------------------------------
__global__ __launch_bounds__(512) void k_bplace(const int* __restrict__ src,
                                                const int* __restrict__ dst,
                                                const int* __restrict__ OFF,
                                                int* __restrict__ pk) {
    __shared__ int cur[NB];
    const int* off = OFF + (size_t)blockIdx.x * NB;
    for (int t = threadIdx.x; t < NB; t += 512) cur[t] = off[t];
    __syncthreads();
    int base = blockIdx.x * EPB;
    int end  = min(base + EPB, N_EDGES);
    for (int i = base + threadIdx.x; i < end; i += 512) {
        int d = dst[i];
        int s = src[i];
        int pos = atomicAdd(&cur[d >> BSHIFT], 1);
        pk[pos] = ((d & (BSIZE - 1)) << 17) | s;
    }
}

// ---------------------------------------------------------------------------
// Pass 1 SpMM: in-block counting sort to exact dst-loc (2 LDS atomics/edge),
// then exclusive-owner segmented gather of fp16 h rows: 12 slots x 5 lanes,
// each lane one aligned half2 (4B). Register acc, non-atomic writes.
// ---------------------------------------------------------------------------
__global__ __launch_bounds__(512) void k_spmm1(const __half* __restrict__ h,
                                               const int* __restrict__ bstart,
                                               const int* __restrict__ pk,
                                               float* __restrict__ part) {
    __shared__ int eh[CAP];
    __shared__ int srt[CAP];
    __shared__ int hist[BSIZE];
    __shared__ int cur[BSIZE];

    int b     = blockIdx.x / CHUNKS;
    int chunk = blockIdx.x % CHUNKS;
    int s0  = bstart[b];
    int len = bstart[b + 1] - s0;
    int c0  = s0 + (len * chunk) / CHUNKS;
    int c1  = s0 + (len * (chunk + 1)) / CHUNKS;
    int n   = c1 - c0;
    int nc  = min(n, CAP);

    for (int t = threadIdx.x; t < BSIZE; t += 512) hist[t] = 0;
    __syncthreads();

    for (int i = threadIdx.x; i < nc; i += 512) {
        int p = pk[c0 + i];
        eh[i] = p;
        atomicAdd(&hist[p >> 17], 1);
    }
    __syncthreads();

    if (threadIdx.x < 64) {
        int l = threadIdx.x;
        int carry = 0;
#pragma unroll
        for (int j = 0; j < 4; ++j) {
            int x = hist[j * 64 + l];
            int v = x;
#pragma unroll
            for (int off = 1; off < 64; off <<= 1) {
                int t2 = __shfl_up(v, off);
                if (l >= off) v += t2;
            }
            cur[j * 64 + l] = carry + v - x;
            carry += __shfl(v, 63);
        }
    }
    __syncthreads();

    for (int i = threadIdx.x; i < nc; i += 512) {
        int p = eh[i];
        int pos = atomicAdd(&cur[p >> 17], 1);
        srt[pos] = p;
    }
    __syncthreads();

    int wave = threadIdx.x >> 6;
    int lane = threadIdx.x & 63;
    int slot = lane / 5;            // 0..12 (12 = idle lanes 60..63)
    int l    = lane - slot * 5;     // half2 index within the row
    float* pb = part + (size_t)blockIdx.x * TILE;
    const __half2* h2 = (const __half2*)h;

    if (slot < 12) {
        int g = wave * 12 + slot;   // 0..95
        for (int loc = g; loc < BSIZE; loc += 96) {
            int e0 = loc ? cur[loc - 1] : 0;
            int e1 = cur[loc];
            float ax0 = 0.f, ay0 = 0.f, ax1 = 0.f, ay1 = 0.f;
            float ax2 = 0.f, ay2 = 0.f, ax3 = 0.f, ay3 = 0.f;
            int e = e0;
            for (; e + 3 < e1; e += 4) {
                int p0 = srt[e] & 0x1FFFF, p1 = srt[e + 1] & 0x1FFFF;
                int p2 = srt[e + 2] & 0x1FFFF, p3 = srt[e + 3] & 0x1FFFF;
                float2 v0 = __half22float2(h2[(size_t)p0 * 5 + l]);
                float2 v1 = __half22float2(h2[(size_t)p1 * 5 + l]);
                float2 v2 = __half22float2(h2[(size_t)p2 * 5 + l]);
                float2 v3 = __half22float2(h2[(size_t)p3 * 5 + l]);
                ax0 += v0.x; ay0 += v0.y; ax1 += v1.x; ay1 += v1.y;
                ax2 += v2.x; ay2 += v2.y; ax3 += v3.x; ay3 += v3.y;
            }
            for (; e < e1; ++e) {
                float2 v = __half22float2(h2[(size_t)(srt[e] & 0x1FFFF) * 5 + l]);
                ax0 += v.x; ay0 += v.y;
            }
            pb[loc * DIM + 2 * l]     = (ax0 + ax1) + (ax2 + ax3);
            pb[loc * DIM + 2 * l + 1] = (ay0 + ay1) + (ay2 + ay3);
        }
    }
    __syncthreads();

    // overflow fallback (statistically never; correctness guard)
    for (int i = CAP + threadIdx.x; i < n; i += 512) {
        int p = pk[c0 + i];
        int loc = p >> 17, s = p & 0x1FFFF;
#pragma unroll
        for (int j = 0; j < 5; ++j) {
            float2 v = __half22float2(h2[(size_t)s * 5 + j]);
            atomicAdd(&pb[loc * DIM + 2 * j], v.x);
            atomicAdd(&pb[loc * DIM + 2 * j + 1], v.y);
        }
    }
}

// merge CHUNKS partials + fused relu -> r (fp16, compact stride 10)
__global__ __launch_bounds__(256) void k_merge_relu(const float* __restrict__ part,
                                                    __half* __restrict__ r) {
    int b     = blockIdx.x;
    int nbase = b << BSHIFT;
    const float* p0 = part + (size_t)(b * CHUNKS) * TILE;
    __half2* r2 = (__half2*)r;
    for (int t = threadIdx.x; t < TILE / 2; t += 256) {     // pairs
        float sx = 0.f, sy = 0.f;
#pragma unroll
        for (int c = 0; c < CHUNKS; ++c) {
            float2 v = ((const float2*)(p0 + (size_t)c * TILE))[t];
            sx += v.x; sy += v.y;
        }
        int ebase = nbase * DIM + 2 * t;                    // global element idx
        if (ebase < N_NODES * DIM)
            r2[(size_t)nbase * 5 + t] = __floats2half2_rn(fmaxf(sx, 0.f), fmaxf(sy, 0.f));
    }
}

// ---------------------------------------------------------------------------
// Pass 2: walk dst-sorted pk; gid(loc) has 1-2 distinct values per bucket ->
// per-slot running register sums, LDS flush only on gid change.
// fp16 r gather (L2-resident), 12 slots x 5 lanes, 4-deep pipeline.
// ---------------------------------------------------------------------------
__global__ __launch_bounds__(512) void k_pass2(const __half* __restrict__ r,
                                               const int* __restrict__ bstart,
                                               const int* __restrict__ pk,
                                               const int* __restrict__ bound,
                                               float* __restrict__ part2) {
    __shared__ float acc[NUM_GRAPHS * ACC_STRIDE];
    __shared__ unsigned char locgid[BSIZE];
    __shared__ int bnd[NUM_GRAPHS + 1];

    int b     = blockIdx.x / CHUNKS;
    int chunk = blockIdx.x % CHUNKS;
    int nbase = b << BSHIFT;

    if (threadIdx.x < NUM_GRAPHS + 1) bnd[threadIdx.x] = bound[threadIdx.x];
    for (int t = threadIdx.x; t < NUM_GRAPHS * ACC_STRIDE; t += 512) acc[t] = 0.f;
    __syncthreads();
    if (threadIdx.x < BSIZE) {
        int node = min(nbase + threadIdx.x, N_NODES - 1);
        int lo = 0, hi = NUM_GRAPHS - 1;
#pragma unroll
        for (int it = 0; it < 6; ++it) {
            int mid = (lo + hi + 1) >> 1;
            if (bnd[mid] <= node) lo = mid; else hi = mid - 1;
        }
        locgid[threadIdx.x] = (unsigned char)lo;
    }
    __syncthreads();

    int s0  = bstart[b];
    int len = bstart[b + 1] - s0;
    int c0  = s0 + (len * chunk) / CHUNKS;
    int c1  = s0 + (len * (chunk + 1)) / CHUNKS;

    int wave = threadIdx.x >> 6;
    int lane = threadIdx.x & 63;
    int slot = lane / 5;
    int l    = lane - slot * 5;
    const __half2* r2 = (const __half2*)r;

    if (slot < 12) {
        const int STR = 96;        // 8 waves * 12 slots
        float sx = 0.f, sy = 0.f;
        int cur = -1;
        int e = c0 + wave * 12 + slot;
#define P2_STEP(pp, vv)                                                    \
        {                                                                  \
            int g_ = locgid[(pp) >> 17];                                   \
            if (g_ != cur) {                                               \
                if (cur >= 0) {                                            \
                    atomicAdd(&acc[cur * ACC_STRIDE + 2 * l], sx);         \
                    atomicAdd(&acc[cur * ACC_STRIDE + 2 * l + 1], sy);     \
                }                                                          \
                sx = 0.f; sy = 0.f; cur = g_;                              \
            }                                                              \
            sx += (vv).x; sy += (vv).y;                                    \
        }
        for (; e + 3 * STR < c1; e += 4 * STR) {
            int p0 = pk[e], p1 = pk[e + STR], p2 = pk[e + 2 * STR], p3 = pk[e + 3 * STR];
            float2 v0 = __half22float2(r2[(size_t)(p0 & 0x1FFFF) * 5 + l]);
            float2 v1 = __half22float2(r2[(size_t)(p1 & 0x1FFFF) * 5 + l]);
            float2 v2 = __half22float2(r2[(size_t)(p2 & 0x1FFFF) * 5 + l]);
            float2 v3 = __half22float2(r2[(size_t)(p3 & 0x1FFFF) * 5 + l]);
            P2_STEP(p0, v0) P2_STEP(p1, v1) P2_STEP(p2, v2) P2_STEP(p3, v3)
        }
        for (; e < c1; e += STR) {
            int p = pk[e];
            float2 v = __half22float2(r2[(size_t)(p & 0x1FFFF) * 5 + l]);
            P2_STEP(p, v)
        }
        if (cur >= 0) {
            atomicAdd(&acc[cur * ACC_STRIDE + 2 * l], sx);
            atomicAdd(&acc[cur * ACC_STRIDE + 2 * l + 1], sy);
        }
#undef P2_STEP
    }
    __syncthreads();

    float* po = part2 + (size_t)blockIdx.x * (NUM_GRAPHS * DIM);
    for (int t = threadIdx.x; t < NUM_GRAPHS * DIM; t += 512)
        po[t] = acc[(t / DIM) * ACC_STRIDE + t % DIM];
}

// sum chunk partials -> sums (6400 global atomics total; sums pre-zeroed)
__global__ __launch_bounds__(640) void k_sums(const float* __restrict__ part2,
                                              float* __restrict__ sums) {
    int t  = threadIdx.x;                 // 0..639 = g*10+k
    int b0 = blockIdx.x * 79;
    int b1 = min(b0 + 79, NCHUNK);
    float s = 0.f;
    for (int c = b0; c < b1; ++c) s += part2[(size_t)c * (NUM_GRAPHS * DIM) + t];
    atomicAdd(&sums[t], s);
}

// out[g] = sigmoid(((sums[g]/max(cnt,1)) @ W2) @ W3)
__global__ void k_final(const float* __restrict__ sums, const int* __restrict__ bound,
                        const float* __restrict__ W2, const float* __restrict__ W3,
                        float* __restrict__ out) {
    int g = threadIdx.x;
    if (g >= NUM_GRAPHS) return;
    float c = fmaxf((float)(bound[g + 1] - bound[g]), 1.f);
    float p[DIM];
#pragma unroll
    for (int k = 0; k < DIM; ++k) p[k] = sums[g * DIM + k] / c;
    float z = 0.f;
#pragma unroll
    for (int j = 0; j < DIM; ++j) {
        float t = 0.f;
#pragma unroll
        for (int k = 0; k < DIM; ++k) t += p[k] * W2[k * DIM + j];
        z += t * W3[j];
    }
    out[g] = 1.f / (1.f + expf(-z));
}

// ---------------------------------------------------------------------------
// Workspace (bytes):
//   h1     [0,         2000000)   100k x 10 fp16 (L2-resident)
//   pk     [2000000,  14800000)   3.2M int, dst-bucket-sorted (both passes)
//   r      [14800000, 16800000)   100k x 10 fp16 (L2-resident)
//   part   [16800000, 24807680)   782 x 2560 f32; part2 (782x640) aliases
//   H/OFF  [24807680, 25208064)   256 x 391 int
//   bstart [25208064, 25209632)   392 int
//   bound  [25209632, 25209892)   65 int
//   sums   [25209892, 25212452)   640 f32   <- zeroed
// ---------------------------------------------------------------------------
extern "C" void kernel_launch(void* const* d_in, const int* in_sizes, int n_in,
                              void* d_out, int out_size, void* d_ws, size_t ws_size,
                              hipStream_t stream) {
    const float* feat = (const float*)d_in[0];
    const float* W1   = (const float*)d_in[1];
    const float* W2   = (const float*)d_in[2];
    const float* W3   = (const float*)d_in[3];
    const int*   src  = (const int*)d_in[4];
    const int*   dst  = (const int*)d_in[5];
    const int*   gids = (const int*)d_in[6];
    float*       out  = (float*)d_out;

    char* ws = (char*)d_ws;
    __half* h1     = (__half*)(ws);
    int*    pk     = (int*)(ws + 2000000);
    __half* r      = (__half*)(ws + 14800000);
    float*  part   = (float*)(ws + 16800000);
    float*  part2  = (float*)(ws + 16800000);  // aliases part (dead after merge)
    int*    H      = (int*)(ws + 24807680);
    int*    bstart = (int*)(ws + 25208064);
    int*    bound  = (int*)(ws + 25209632);
    float*  sums   = (float*)(ws + 25209892);

    hipMemsetAsync(sums, 0, 2560, stream);

    k_gemm_w1<<<(N_NODES * 32 + 255) / 256, 256, 0, stream>>>(feat, W1, h1);
    k_bounds <<<(N_NODES + 255) / 256, 256, 0, stream>>>(gids, bound);
    k_hist   <<<EBLOCKS, 512, 0, stream>>>(dst, H);
    k_scan   <<<1, 512, 0, stream>>>(H, bstart);
    k_bplace <<<EBLOCKS, 512, 0, stream>>>(src, dst, H, pk);

    k_spmm1     <<<NCHUNK, 512, 0, stream>>>(h1, bstart, pk, part);
    k_merge_relu<<<NB, 256, 0, stream>>>(part, r);
    k_pass2     <<<NCHUNK, 512, 0, stream>>>(r, bstart, pk, bound, part2);
    k_sums      <<<(NCHUNK + 78) / 79, 640, 0, stream>>>(part2, sums);

    k_final<<<1, 64, 0, stream>>>(sums, bound, W2, W3, out);
}

// Round 12
// 282.221 us; speedup vs baseline: 1.2126x; 1.1704x over previous
//
#include <hip/hip_runtime.h>
#include <hip/hip_fp16.h>

#define N_NODES 100000
#define N_EDGES 3200000
#define NUM_FEATURES 128
#define DIM 10
#define NUM_GRAPHS 64

#define BSHIFT 8                             // 256 nodes per bucket
#define BSIZE (1 << BSHIFT)
#define NB ((N_NODES + BSIZE - 1) / BSIZE)   // 391 buckets
#define CHUNKS 2                             // spmm1 chunks per bucket
#define PCHUNKS 4                            // pass2 chunks per bucket
#define EPB 12500                            // edges per hist/place block
#define EBLOCKS 256                          // 256 * 12500 = 3.2M exact
#define TILE (BSIZE * DIM)                   // 2560 floats per bucket tile
#define CAP 4608                             // max edges per spmm1 chunk (~+11 sigma)
#define NCHUNK (NB * CHUNKS)                 // 782
#define NCHUNK2 (NB * PCHUNKS)               // 1564
#define ACC_STRIDE 11

// ---------------------------------------------------------------------------
// h1 = features @ W1 -> fp16, compact stride 10 (2 MB total: L2-resident)
// ---------------------------------------------------------------------------
__global__ __launch_bounds__(256) void k_gemm_w1(const float* __restrict__ feat,
                                                 const float* __restrict__ W1,
                                                 __half* __restrict__ h1) {
    int gid  = blockIdx.x * blockDim.x + threadIdx.x;
    int node = gid >> 5;
    int lane = gid & 31;
    if (node >= N_NODES) return;

    float w[4][DIM];
#pragma unroll
    for (int j = 0; j < 4; ++j)
#pragma unroll
        for (int k = 0; k < DIM; ++k)
            w[j][k] = W1[(lane * 4 + j) * DIM + k];

    const float4 f = *reinterpret_cast<const float4*>(feat + (size_t)node * NUM_FEATURES + lane * 4);
    float fv[4] = {f.x, f.y, f.z, f.w};

    float acc[DIM];
#pragma unroll
    for (int k = 0; k < DIM; ++k) acc[k] = 0.f;
#pragma unroll
    for (int j = 0; j < 4; ++j)
#pragma unroll
        for (int k = 0; k < DIM; ++k)
            acc[k] += fv[j] * w[j][k];

#pragma unroll
    for (int off = 16; off > 0; off >>= 1)
#pragma unroll
        for (int k = 0; k < DIM; ++k)
            acc[k] += __shfl_xor(acc[k], off);

    if (lane == 0) {
        __half2* o = (__half2*)h1;
#pragma unroll
        for (int j = 0; j < 5; ++j)
            o[(size_t)node * 5 + j] = __floats2half2_rn(acc[2 * j], acc[2 * j + 1]);
    }
}

// ---------------------------------------------------------------------------
// Graph boundaries from sorted gids
// ---------------------------------------------------------------------------
__global__ __launch_bounds__(256) void k_bounds(const int* __restrict__ gids,
                                                int* __restrict__ bound) {
    int n = blockIdx.x * blockDim.x + threadIdx.x;
    if (n >= N_NODES) return;
    int g  = gids[n];
    int gp = n ? gids[n - 1] : -1;
    for (int v = gp + 1; v <= g; ++v) bound[v] = n;
    if (n == N_NODES - 1)
        for (int v = g + 1; v <= NUM_GRAPHS; ++v) bound[v] = N_NODES;
}

// ---------------------------------------------------------------------------
// Per-block dst-bucket histogram -> H[block][bin].  4-batched loads so each
// wave keeps 4 global loads in flight before the vmcnt-forcing LDS atomics.
// ---------------------------------------------------------------------------
__global__ __launch_bounds__(512) void k_hist(const int* __restrict__ dst,
                                              int* __restrict__ H) {
    __shared__ int hd[NB];
    for (int t = threadIdx.x; t < NB; t += 512) hd[t] = 0;
    __syncthreads();
    int base = blockIdx.x * EPB;
    int end  = min(base + EPB, N_EDGES);
    int i = base + threadIdx.x;
    for (; i + 1536 < end; i += 2048) {
        int d0 = dst[i], d1 = dst[i + 512], d2 = dst[i + 1024], d3 = dst[i + 1536];
        atomicAdd(&hd[d0 >> BSHIFT], 1);
        atomicAdd(&hd[d1 >> BSHIFT], 1);
        atomicAdd(&hd[d2 >> BSHIFT], 1);
        atomicAdd(&hd[d3 >> BSHIFT], 1);
    }
    for (; i < end; i += 512)
        atomicAdd(&hd[dst[i] >> BSHIFT], 1);
    __syncthreads();
    int* Hrow = H + (size_t)blockIdx.x * NB;
    for (int t = threadIdx.x; t < NB; t += 512) Hrow[t] = hd[t];
}

// ---------------------------------------------------------------------------
// Convert H to per-(block,bin) start offsets in place; emit bstart[NB+1].
// ---------------------------------------------------------------------------
__global__ __launch_bounds__(512) void k_scan(int* __restrict__ H,
                                              int* __restrict__ bstart) {
    __shared__ int ld[512];
    int t = threadIdx.x;
    int tot = 0;
    if (t < NB)
        for (int bk = 0; bk < EBLOCKS; ++bk) tot += H[(size_t)bk * NB + t];
    ld[t] = (t < NB) ? tot : 0;
    __syncthreads();
    for (int off = 1; off < 512; off <<= 1) {
        int v = (t >= off) ? ld[t - off] : 0;
        __syncthreads();
        ld[t] += v;
        __syncthreads();
    }
    int base = t ? ld[t - 1] : 0;
    if (t < NB) bstart[t] = base;
    if (t == NB - 1) bstart[NB] = ld[t];
    if (t < NB) {
        int run = base;
        for (int bk = 0; bk < EBLOCKS; ++bk) {
            int x = H[(size_t)bk * NB + t];
            H[(size_t)bk * NB + t] = run;
            run += x;
        }
    }
}

// ---------------------------------------------------------------------------
// Placement with precomputed cursors, 4-batched loads (8 in flight).
// pk[pos] = (dst&255)<<17 | src
// ---------------------------------------------------------------------------
__global__ __launch_bounds__(512) void k_bplace(const int* __restrict__ src,
                                                const int* __restrict__ dst,
                                                const int* __restrict__ OFF,
                                                int* __restrict__ pk) {
    __shared__ int cur[NB];
    const int* off = OFF + (size_t)blockIdx.x * NB;
    for (int t = threadIdx.x; t < NB; t += 512) cur[t] = off[t];
    __syncthreads();
    int base = blockIdx.x * EPB;
    int end  = min(base + EPB, N_EDGES);
    int i = base + threadIdx.x;
    for (; i + 1536 < end; i += 2048) {
        int d0 = dst[i], d1 = dst[i + 512], d2 = dst[i + 1024], d3 = dst[i + 1536];
        int s0 = src[i], s1 = src[i + 512], s2 = src[i + 1024], s3 = src[i + 1536];
        int q0 = atomicAdd(&cur[d0 >> BSHIFT], 1);
        int q1 = atomicAdd(&cur[d1 >> BSHIFT], 1);
        int q2 = atomicAdd(&cur[d2 >> BSHIFT], 1);
        int q3 = atomicAdd(&cur[d3 >> BSHIFT], 1);
        pk[q0] = ((d0 & (BSIZE - 1)) << 17) | s0;
        pk[q1] = ((d1 & (BSIZE - 1)) << 17) | s1;
        pk[q2] = ((d2 & (BSIZE - 1)) << 17) | s2;
        pk[q3] = ((d3 & (BSIZE - 1)) << 17) | s3;
    }
    for (; i < end; i += 512) {
        int d = dst[i];
        int s = src[i];
        int pos = atomicAdd(&cur[d >> BSHIFT], 1);
        pk[pos] = ((d & (BSIZE - 1)) << 17) | s;
    }
}

// ---------------------------------------------------------------------------
// Pass 1 SpMM: in-block counting sort to exact dst-loc (2 LDS atomics/edge,
// 4-batched pk loads), then exclusive-owner segmented gather (12 slots x 5
// lanes, 8-deep), register acc, non-atomic writes.
// ---------------------------------------------------------------------------
__global__ __launch_bounds__(512) void k_spmm1(const __half* __restrict__ h,
                                               const int* __restrict__ bstart,
                                               const int* __restrict__ pk,
                                               float* __restrict__ part) {
    __shared__ int eh[CAP];
    __shared__ int srt[CAP];
    __shared__ int hist[BSIZE];
    __shared__ int cur[BSIZE];

    int b     = blockIdx.x / CHUNKS;
    int chunk = blockIdx.x % CHUNKS;
    int s0  = bstart[b];
    int len = bstart[b + 1] - s0;
    int c0  = s0 + (len * chunk) / CHUNKS;
    int c1  = s0 + (len * (chunk + 1)) / CHUNKS;
    int n   = c1 - c0;
    int nc  = min(n, CAP);

    for (int t = threadIdx.x; t < BSIZE; t += 512) hist[t] = 0;
    __syncthreads();

    // phase 1: stash + histogram, 4-batched global loads
    {
        int i = threadIdx.x;
        for (; i + 1536 < nc; i += 2048) {
            int p0 = pk[c0 + i],        p1 = pk[c0 + i + 512];
            int p2 = pk[c0 + i + 1024], p3 = pk[c0 + i + 1536];
            eh[i] = p0; eh[i + 512] = p1; eh[i + 1024] = p2; eh[i + 1536] = p3;
            atomicAdd(&hist[p0 >> 17], 1);
            atomicAdd(&hist[p1 >> 17], 1);
            atomicAdd(&hist[p2 >> 17], 1);
            atomicAdd(&hist[p3 >> 17], 1);
        }
        for (; i < nc; i += 512) {
            int p = pk[c0 + i];
            eh[i] = p;
            atomicAdd(&hist[p >> 17], 1);
        }
    }
    __syncthreads();

    // phase 2: exclusive scan (wave 0)
    if (threadIdx.x < 64) {
        int l = threadIdx.x;
        int carry = 0;
#pragma unroll
        for (int j = 0; j < 4; ++j) {
            int x = hist[j * 64 + l];
            int v = x;
#pragma unroll
            for (int off = 1; off < 64; off <<= 1) {
                int t2 = __shfl_up(v, off);
                if (l >= off) v += t2;
            }
            cur[j * 64 + l] = carry + v - x;
            carry += __shfl(v, 63);
        }
    }
    __syncthreads();

    // phase 3: scatter into sorted order (LDS only)
    for (int i = threadIdx.x; i < nc; i += 512) {
        int p = eh[i];
        int pos = atomicAdd(&cur[p >> 17], 1);
        srt[pos] = p;
    }
    __syncthreads();

    // phase 4: segmented gather, 8-deep, register acc, exclusive writes
    int wave = threadIdx.x >> 6;
    int lane = threadIdx.x & 63;
    int slot = lane / 5;            // 0..12 (12 = idle lanes 60..63)
    int l    = lane - slot * 5;     // half2 index within the row
    float* pb = part + (size_t)blockIdx.x * TILE;
    const __half2* h2 = (const __half2*)h;

    if (slot < 12) {
        int g = wave * 12 + slot;   // 0..95
        for (int loc = g; loc < BSIZE; loc += 96) {
            int e0 = loc ? cur[loc - 1] : 0;
            int e1 = cur[loc];
            float ax0 = 0.f, ay0 = 0.f, ax1 = 0.f, ay1 = 0.f;
            float ax2 = 0.f, ay2 = 0.f, ax3 = 0.f, ay3 = 0.f;
            int e = e0;
            for (; e + 7 < e1; e += 8) {
                float2 v0 = __half22float2(h2[(size_t)(srt[e]     & 0x1FFFF) * 5 + l]);
                float2 v1 = __half22float2(h2[(size_t)(srt[e + 1] & 0x1FFFF) * 5 + l]);
                float2 v2 = __half22float2(h2[(size_t)(srt[e + 2] & 0x1FFFF) * 5 + l]);
                float2 v3 = __half22float2(h2[(size_t)(srt[e + 3] & 0x1FFFF) * 5 + l]);
                float2 v4 = __half22float2(h2[(size_t)(srt[e + 4] & 0x1FFFF) * 5 + l]);
                float2 v5 = __half22float2(h2[(size_t)(srt[e + 5] & 0x1FFFF) * 5 + l]);
                float2 v6 = __half22float2(h2[(size_t)(srt[e + 6] & 0x1FFFF) * 5 + l]);
                float2 v7 = __half22float2(h2[(size_t)(srt[e + 7] & 0x1FFFF) * 5 + l]);
                ax0 += v0.x + v4.x; ay0 += v0.y + v4.y;
                ax1 += v1.x + v5.x; ay1 += v1.y + v5.y;
                ax2 += v2.x + v6.x; ay2 += v2.y + v6.y;
                ax3 += v3.x + v7.x; ay3 += v3.y + v7.y;
            }
            for (; e < e1; ++e) {
                float2 v = __half22float2(h2[(size_t)(srt[e] & 0x1FFFF) * 5 + l]);
                ax0 += v.x; ay0 += v.y;
            }
            pb[loc * DIM + 2 * l]     = (ax0 + ax1) + (ax2 + ax3);
            pb[loc * DIM + 2 * l + 1] = (ay0 + ay1) + (ay2 + ay3);
        }
    }
    __syncthreads();

    // overflow fallback (statistically never; correctness guard)
    for (int i = CAP + threadIdx.x; i < n; i += 512) {
        int p = pk[c0 + i];
        int loc = p >> 17, s = p & 0x1FFFF;
#pragma unroll
        for (int j = 0; j < 5; ++j) {
            float2 v = __half22float2(h2[(size_t)s * 5 + j]);
            atomicAdd(&pb[loc * DIM + 2 * j], v.x);
            atomicAdd(&pb[loc * DIM + 2 * j + 1], v.y);
        }
    }
}

// merge CHUNKS partials + fused relu -> r (fp16, compact stride 10)
__global__ __launch_bounds__(256) void k_merge_relu(const float* __restrict__ part,
                                                    __half* __restrict__ r) {
    int b     = blockIdx.x;
    int nbase = b << BSHIFT;
    const float* p0 = part + (size_t)(b * CHUNKS) * TILE;
    __half2* r2 = (__half2*)r;
    for (int t = threadIdx.x; t < TILE / 2; t += 256) {     // pairs
        float sx = 0.f, sy = 0.f;
#pragma unroll
        for (int c = 0; c < CHUNKS; ++c) {
            float2 v = ((const float2*)(p0 + (size_t)c * TILE))[t];
            sx += v.x; sy += v.y;
        }
        int ebase = nbase * DIM + 2 * t;                    // global element idx
        if (ebase < N_NODES * DIM)
            r2[(size_t)nbase * 5 + t] = __floats2half2_rn(fmaxf(sx, 0.f), fmaxf(sy, 0.f));
    }
}

// ---------------------------------------------------------------------------
// Pass 2: walk dst-sorted pk. FAST PATH (~84% of buckets): gid uniform over
// the bucket -> inner loop is pure load+add (no LDS read, no branch, no
// per-edge atomic; 2 LDS atomics per slot total). Slow path keeps the
// running-sum flush (correct for arbitrary loc order).
// ---------------------------------------------------------------------------
__global__ __launch_bounds__(512) void k_pass2(const __half* __restrict__ r,
                                               const int* __restrict__ bstart,
                                               const int* __restrict__ pk,
                                               const int* __restrict__ bound,
                                               float* __restrict__ part2) {
    __shared__ float acc[NUM_GRAPHS * ACC_STRIDE];
    __shared__ unsigned char locgid[BSIZE];
    __shared__ int bnd[NUM_GRAPHS + 1];

    int b     = blockIdx.x / PCHUNKS;
    int chunk = blockIdx.x % PCHUNKS;
    int nbase = b << BSHIFT;

    if (threadIdx.x < NUM_GRAPHS + 1) bnd[threadIdx.x] = bound[threadIdx.x];
    for (int t = threadIdx.x; t < NUM_GRAPHS * ACC_STRIDE; t += 512) acc[t] = 0.f;
    __syncthreads();
    if (threadIdx.x < BSIZE) {
        int node = min(nbase + threadIdx.x, N_NODES - 1);
        int lo = 0, hi = NUM_GRAPHS - 1;
#pragma unroll
        for (int it = 0; it < 6; ++it) {
            int mid = (lo + hi + 1) >> 1;
            if (bnd[mid] <= node) lo = mid; else hi = mid - 1;
        }
        locgid[threadIdx.x] = (unsigned char)lo;
    }
    __syncthreads();

    int s0  = bstart[b];
    int len = bstart[b + 1] - s0;
    int c0  = s0 + (len * chunk) / PCHUNKS;
    int c1  = s0 + (len * (chunk + 1)) / PCHUNKS;

    int wave = threadIdx.x >> 6;
    int lane = threadIdx.x & 63;
    int slot = lane / 5;
    int l    = lane - slot * 5;
    const __half2* r2 = (const __half2*)r;
    bool uni = (locgid[0] == locgid[BSIZE - 1]);
    int  gu  = locgid[0];

    if (slot < 12) {
        const int STR = 96;        // 8 waves * 12 slots
        int e = c0 + wave * 12 + slot;
        if (uni) {
            // FAST PATH: pure gather-accumulate, flush once
            float sx0 = 0.f, sy0 = 0.f, sx1 = 0.f, sy1 = 0.f;
            bool any = (e < c1);
            for (; e + 3 * STR < c1; e += 4 * STR) {
                float2 v0 = __half22float2(r2[(size_t)(pk[e]           & 0x1FFFF) * 5 + l]);
                float2 v1 = __half22float2(r2[(size_t)(pk[e + STR]     & 0x1FFFF) * 5 + l]);
                float2 v2 = __half22float2(r2[(size_t)(pk[e + 2 * STR] & 0x1FFFF) * 5 + l]);
                float2 v3 = __half22float2(r2[(size_t)(pk[e + 3 * STR] & 0x1FFFF) * 5 + l]);
                sx0 += v0.x + v2.x; sy0 += v0.y + v2.y;
                sx1 += v1.x + v3.x; sy1 += v1.y + v3.y;
            }
            for (; e < c1; e += STR) {
                float2 v = __half22float2(r2[(size_t)(pk[e] & 0x1FFFF) * 5 + l]);
                sx0 += v.x; sy0 += v.y;
            }
            if (any) {
                atomicAdd(&acc[gu * ACC_STRIDE + 2 * l], sx0 + sx1);
                atomicAdd(&acc[gu * ACC_STRIDE + 2 * l + 1], sy0 + sy1);
            }
        } else {
            // SLOW PATH: running sum with flush on gid change
            float sx = 0.f, sy = 0.f;
            int cur = -1;
#define P2_STEP(pp, vv)                                                    \
            {                                                              \
                int g_ = locgid[(pp) >> 17];                               \
                if (g_ != cur) {                                           \
                    if (cur >= 0) {                                        \
                        atomicAdd(&acc[cur * ACC_STRIDE + 2 * l], sx);     \
                        atomicAdd(&acc[cur * ACC_STRIDE + 2 * l + 1], sy); \
                    }                                                      \
                    sx = 0.f; sy = 0.f; cur = g_;                          \
                }                                                          \
                sx += (vv).x; sy += (vv).y;                                \
            }
            for (; e + 3 * STR < c1; e += 4 * STR) {
                int p0 = pk[e], p1 = pk[e + STR], p2 = pk[e + 2 * STR], p3 = pk[e + 3 * STR];
                float2 v0 = __half22float2(r2[(size_t)(p0 & 0x1FFFF) * 5 + l]);
                float2 v1 = __half22float2(r2[(size_t)(p1 & 0x1FFFF) * 5 + l]);
                float2 v2 = __half22float2(r2[(size_t)(p2 & 0x1FFFF) * 5 + l]);
                float2 v3 = __half22float2(r2[(size_t)(p3 & 0x1FFFF) * 5 + l]);
                P2_STEP(p0, v0) P2_STEP(p1, v1) P2_STEP(p2, v2) P2_STEP(p3, v3)
            }
            for (; e < c1; e += STR) {
                int p = pk[e];
                float2 v = __half22float2(r2[(size_t)(p & 0x1FFFF) * 5 + l]);
                P2_STEP(p, v)
            }
            if (cur >= 0) {
                atomicAdd(&acc[cur * ACC_STRIDE + 2 * l], sx);
                atomicAdd(&acc[cur * ACC_STRIDE + 2 * l + 1], sy);
            }
#undef P2_STEP
        }
    }
    __syncthreads();

    float* po = part2 + (size_t)blockIdx.x * (NUM_GRAPHS * DIM);
    for (int t = threadIdx.x; t < NUM_GRAPHS * DIM; t += 512)
        po[t] = acc[(t / DIM) * ACC_STRIDE + t % DIM];
}

// sum chunk partials -> sums (6400 global atomics total; sums pre-zeroed)
__global__ __launch_bounds__(640) void k_sums(const float* __restrict__ part2,
                                              float* __restrict__ sums) {
    int t  = threadIdx.x;                 // 0..639 = g*10+k
    int b0 = blockIdx.x * 79;
    int b1 = min(b0 + 79, NCHUNK2);
    float s = 0.f;
    for (int c = b0; c < b1; ++c) s += part2[(size_t)c * (NUM_GRAPHS * DIM) + t];
    atomicAdd(&sums[t], s);
}

// out[g] = sigmoid(((sums[g]/max(cnt,1)) @ W2) @ W3)
__global__ void k_final(const float* __restrict__ sums, const int* __restrict__ bound,
                        const float* __restrict__ W2, const float* __restrict__ W3,
                        float* __restrict__ out) {
    int g = threadIdx.x;
    if (g >= NUM_GRAPHS) return;
    float c = fmaxf((float)(bound[g + 1] - bound[g]), 1.f);
    float p[DIM];
#pragma unroll
    for (int k = 0; k < DIM; ++k) p[k] = sums[g * DIM + k] / c;
    float z = 0.f;
#pragma unroll
    for (int j = 0; j < DIM; ++j) {
        float t = 0.f;
#pragma unroll
        for (int k = 0; k < DIM; ++k) t += p[k] * W2[k * DIM + j];
        z += t * W3[j];
    }
    out[g] = 1.f / (1.f + expf(-z));
}

// ---------------------------------------------------------------------------
// Workspace (bytes):
//   h1     [0,         2000000)   100k x 10 fp16 (L2-resident)
//   pk     [2000000,  14800000)   3.2M int, dst-bucket-sorted (both passes)
//   r      [14800000, 16800000)   100k x 10 fp16 (L2-resident)
//   part   [16800000, 24807680)   782 x 2560 f32; part2 (1564x640) aliases
//   H/OFF  [24807680, 25208064)   256 x 391 int
//   bstart [25208064, 25209632)   392 int
//   bound  [25209632, 25209892)   65 int
//   sums   [25209892, 25212452)   640 f32   <- zeroed
// ---------------------------------------------------------------------------
extern "C" void kernel_launch(void* const* d_in, const int* in_sizes, int n_in,
                              void* d_out, int out_size, void* d_ws, size_t ws_size,
                              hipStream_t stream) {
    const float* feat = (const float*)d_in[0];
    const float* W1   = (const float*)d_in[1];
    const float* W2   = (const float*)d_in[2];
    const float* W3   = (const float*)d_in[3];
    const int*   src  = (const int*)d_in[4];
    const int*   dst  = (const int*)d_in[5];
    const int*   gids = (const int*)d_in[6];
    float*       out  = (float*)d_out;

    char* ws = (char*)d_ws;
    __half* h1     = (__half*)(ws);
    int*    pk     = (int*)(ws + 2000000);
    __half* r      = (__half*)(ws + 14800000);
    float*  part   = (float*)(ws + 16800000);
    float*  part2  = (float*)(ws + 16800000);  // aliases part (dead after merge)
    int*    H      = (int*)(ws + 24807680);
    int*    bstart = (int*)(ws + 25208064);
    int*    bound  = (int*)(ws + 25209632);
    float*  sums   = (float*)(ws + 25209892);

    hipMemsetAsync(sums, 0, 2560, stream);

    k_gemm_w1<<<(N_NODES * 32 + 255) / 256, 256, 0, stream>>>(feat, W1, h1);
    k_bounds <<<(N_NODES + 255) / 256, 256, 0, stream>>>(gids, bound);
    k_hist   <<<EBLOCKS, 512, 0, stream>>>(dst, H);
    k_scan   <<<1, 512, 0, stream>>>(H, bstart);
    k_bplace <<<EBLOCKS, 512, 0, stream>>>(src, dst, H, pk);

    k_spmm1     <<<NCHUNK, 512, 0, stream>>>(h1, bstart, pk, part);
    k_merge_relu<<<NB, 256, 0, stream>>>(part, r);
    k_pass2     <<<NCHUNK2, 512, 0, stream>>>(r, bstart, pk, bound, part2);
    k_sums      <<<(NCHUNK2 + 78) / 79, 640, 0, stream>>>(part2, sums);

    k_final<<<1, 64, 0, stream>>>(sums, bound, W2, W3, out);
}

// Round 13
// 230.957 us; speedup vs baseline: 1.4818x; 1.2220x over previous
//
#include <hip/hip_runtime.h>
#include <hip/hip_fp16.h>

#define N_NODES 100000
#define N_EDGES 3200000
#define NUM_FEATURES 128
#define DIM 10
#define NUM_GRAPHS 64

#define BSHIFT 8                             // 256 nodes per bucket
#define BSIZE (1 << BSHIFT)
#define NB ((N_NODES + BSIZE - 1) / BSIZE)   // 391 buckets
#define CHUNKS 2                             // spmm1 chunks per bucket
#define PCHUNKS 4                            // pass2 chunks per bucket
#define EPB 12500                            // edges per hist/place block
#define EBLOCKS 256                          // 256 * 12500 = 3.2M exact
#define TILE (BSIZE * DIM)                   // 2560 floats per bucket tile
#define CAP 4608                             // max edges per spmm1 chunk (~+11 sigma)
#define NCHUNK (NB * CHUNKS)                 // 782
#define NCHUNK2 (NB * PCHUNKS)               // 1564
#define ACC_STRIDE 11

// ---------------------------------------------------------------------------
// h1 = features @ W1 -> fp16 compact stride 10 (2 MB, L2-resident).
// Fused: first 391 blocks also compute graph boundaries from sorted gids.
// ---------------------------------------------------------------------------
__global__ __launch_bounds__(256) void k_gemm_w1(const float* __restrict__ feat,
                                                 const float* __restrict__ W1,
                                                 __half* __restrict__ h1,
                                                 const int* __restrict__ gids,
                                                 int* __restrict__ bound) {
    // fused bounds
    int nb2 = blockIdx.x * 256 + threadIdx.x;
    if (blockIdx.x < 391 && nb2 < N_NODES) {
        int g  = gids[nb2];
        int gp = nb2 ? gids[nb2 - 1] : -1;
        for (int v = gp + 1; v <= g; ++v) bound[v] = nb2;
        if (nb2 == N_NODES - 1)
            for (int v = g + 1; v <= NUM_GRAPHS; ++v) bound[v] = N_NODES;
    }

    int gid  = blockIdx.x * blockDim.x + threadIdx.x;
    int node = gid >> 5;
    int lane = gid & 31;
    if (node >= N_NODES) return;

    float w[4][DIM];
#pragma unroll
    for (int j = 0; j < 4; ++j)
#pragma unroll
        for (int k = 0; k < DIM; ++k)
            w[j][k] = W1[(lane * 4 + j) * DIM + k];

    const float4 f = *reinterpret_cast<const float4*>(feat + (size_t)node * NUM_FEATURES + lane * 4);
    float fv[4] = {f.x, f.y, f.z, f.w};

    float acc[DIM];
#pragma unroll
    for (int k = 0; k < DIM; ++k) acc[k] = 0.f;
#pragma unroll
    for (int j = 0; j < 4; ++j)
#pragma unroll
        for (int k = 0; k < DIM; ++k)
            acc[k] += fv[j] * w[j][k];

#pragma unroll
    for (int off = 16; off > 0; off >>= 1)
#pragma unroll
        for (int k = 0; k < DIM; ++k)
            acc[k] += __shfl_xor(acc[k], off);

    if (lane == 0) {
        __half2* o = (__half2*)h1;
#pragma unroll
        for (int j = 0; j < 5; ++j)
            o[(size_t)node * 5 + j] = __floats2half2_rn(acc[2 * j], acc[2 * j + 1]);
    }
}

// ---------------------------------------------------------------------------
// Per-block dst-bucket histogram -> H[block][bin], 4-batched loads.
// ---------------------------------------------------------------------------
__global__ __launch_bounds__(512) void k_hist(const int* __restrict__ dst,
                                              int* __restrict__ H) {
    __shared__ int hd[NB];
    for (int t = threadIdx.x; t < NB; t += 512) hd[t] = 0;
    __syncthreads();
    int base = blockIdx.x * EPB;
    int end  = min(base + EPB, N_EDGES);
    int i = base + threadIdx.x;
    for (; i + 1536 < end; i += 2048) {
        int d0 = dst[i], d1 = dst[i + 512], d2 = dst[i + 1024], d3 = dst[i + 1536];
        atomicAdd(&hd[d0 >> BSHIFT], 1);
        atomicAdd(&hd[d1 >> BSHIFT], 1);
        atomicAdd(&hd[d2 >> BSHIFT], 1);
        atomicAdd(&hd[d3 >> BSHIFT], 1);
    }
    for (; i < end; i += 512)
        atomicAdd(&hd[dst[i] >> BSHIFT], 1);
    __syncthreads();
    int* Hrow = H + (size_t)blockIdx.x * NB;
    for (int t = threadIdx.x; t < NB; t += 512) Hrow[t] = hd[t];
}

// ---------------------------------------------------------------------------
// Parallel scan stage 1: one block per bin; block-scan the 256 per-histblock
// counts -> exclusive prefixes (in place) + bin total.
// ---------------------------------------------------------------------------
__global__ __launch_bounds__(256) void k_scan1(int* __restrict__ H,
                                               int* __restrict__ tot) {
    __shared__ int ld[256];
    int bin = blockIdx.x;
    int t   = threadIdx.x;
    int x   = H[(size_t)t * NB + bin];
    ld[t] = x;
    __syncthreads();
    for (int off = 1; off < 256; off <<= 1) {
        int v = (t >= off) ? ld[t - off] : 0;
        __syncthreads();
        ld[t] += v;
        __syncthreads();
    }
    H[(size_t)t * NB + bin] = ld[t] - x;   // exclusive
    if (t == 255) tot[bin] = ld[t];
}

// ---------------------------------------------------------------------------
// Scan stage 2: exclusive scan of 391 bin totals -> base/bstart; zero sums.
// ---------------------------------------------------------------------------
__global__ __launch_bounds__(704) void k_scan2(const int* __restrict__ tot,
                                               int* __restrict__ base,
                                               int* __restrict__ bstart,
                                               float* __restrict__ sums) {
    __shared__ int ld[512];
    int t = threadIdx.x;
    if (t < 512) ld[t] = (t < NB) ? tot[t] : 0;
    __syncthreads();
    for (int off = 1; off < 512; off <<= 1) {
        int v = (t >= off && t < 512) ? ld[t - off] : 0;
        __syncthreads();
        if (t < 512) ld[t] += v;
        __syncthreads();
    }
    if (t < NB) {
        int excl = t ? ld[t - 1] : 0;
        base[t]   = excl;
        bstart[t] = excl;
    }
    if (t == NB - 1) bstart[NB] = ld[t];
    if (t < NUM_GRAPHS * DIM) sums[t] = 0.f;
}

// ---------------------------------------------------------------------------
// Placement: cursor = per-(block,bin) exclusive + bin base; 1 LDS atomic/edge,
// 4-batched loads. pk[pos] = (dst&255)<<17 | src
// ---------------------------------------------------------------------------
__global__ __launch_bounds__(512) void k_bplace(const int* __restrict__ src,
                                                const int* __restrict__ dst,
                                                const int* __restrict__ OFF,
                                                const int* __restrict__ base,
                                                int* __restrict__ pk) {
    __shared__ int cur[NB];
    const int* off = OFF + (size_t)blockIdx.x * NB;
    for (int t = threadIdx.x; t < NB; t += 512) cur[t] = off[t] + base[t];
    __syncthreads();
    int b0  = blockIdx.x * EPB;
    int end = min(b0 + EPB, N_EDGES);
    int i = b0 + threadIdx.x;
    for (; i + 1536 < end; i += 2048) {
        int d0 = dst[i], d1 = dst[i + 512], d2 = dst[i + 1024], d3 = dst[i + 1536];
        int s0 = src[i], s1 = src[i + 512], s2 = src[i + 1024], s3 = src[i + 1536];
        int q0 = atomicAdd(&cur[d0 >> BSHIFT], 1);
        int q1 = atomicAdd(&cur[d1 >> BSHIFT], 1);
        int q2 = atomicAdd(&cur[d2 >> BSHIFT], 1);
        int q3 = atomicAdd(&cur[d3 >> BSHIFT], 1);
        pk[q0] = ((d0 & (BSIZE - 1)) << 17) | s0;
        pk[q1] = ((d1 & (BSIZE - 1)) << 17) | s1;
        pk[q2] = ((d2 & (BSIZE - 1)) << 17) | s2;
        pk[q3] = ((d3 & (BSIZE - 1)) << 17) | s3;
    }
    for (; i < end; i += 512) {
        int d = dst[i];
        int s = src[i];
        int pos = atomicAdd(&cur[d >> BSHIFT], 1);
        pk[pos] = ((d & (BSIZE - 1)) << 17) | s;
    }
}

// ---------------------------------------------------------------------------
// Pass 1 SpMM: in-block counting sort to exact dst-loc (2 LDS atomics/edge,
// 4-batched pk loads), then exclusive-owner segmented gather (12 slots x 5
// lanes, 8-deep), register acc, non-atomic writes.
// ---------------------------------------------------------------------------
__global__ __launch_bounds__(512) void k_spmm1(const __half* __restrict__ h,
                                               const int* __restrict__ bstart,
                                               const int* __restrict__ pk,
                                               float* __restrict__ part) {
    __shared__ int eh[CAP];
    __shared__ int srt[CAP];
    __shared__ int hist[BSIZE];
    __shared__ int cur[BSIZE];

    int b     = blockIdx.x / CHUNKS;
    int chunk = blockIdx.x % CHUNKS;
    int s0  = bstart[b];
    int len = bstart[b + 1] - s0;
    int c0  = s0 + (len * chunk) / CHUNKS;
    int c1  = s0 + (len * (chunk + 1)) / CHUNKS;
    int n   = c1 - c0;
    int nc  = min(n, CAP);

    for (int t = threadIdx.x; t < BSIZE; t += 512) hist[t] = 0;
    __syncthreads();

    {
        int i = threadIdx.x;
        for (; i + 1536 < nc; i += 2048) {
            int p0 = pk[c0 + i],        p1 = pk[c0 + i + 512];
            int p2 = pk[c0 + i + 1024], p3 = pk[c0 + i + 1536];
            eh[i] = p0; eh[i + 512] = p1; eh[i + 1024] = p2; eh[i + 1536] = p3;
            atomicAdd(&hist[p0 >> 17], 1);
            atomicAdd(&hist[p1 >> 17], 1);
            atomicAdd(&hist[p2 >> 17], 1);
            atomicAdd(&hist[p3 >> 17], 1);
        }
        for (; i < nc; i += 512) {
            int p = pk[c0 + i];
            eh[i] = p;
            atomicAdd(&hist[p >> 17], 1);
        }
    }
    __syncthreads();

    if (threadIdx.x < 64) {
        int l = threadIdx.x;
        int carry = 0;
#pragma unroll
        for (int j = 0; j < 4; ++j) {
            int x = hist[j * 64 + l];
            int v = x;
#pragma unroll
            for (int off = 1; off < 64; off <<= 1) {
                int t2 = __shfl_up(v, off);
                if (l >= off) v += t2;
            }
            cur[j * 64 + l] = carry + v - x;
            carry += __shfl(v, 63);
        }
    }
    __syncthreads();

    for (int i = threadIdx.x; i < nc; i += 512) {
        int p = eh[i];
        int pos = atomicAdd(&cur[p >> 17], 1);
        srt[pos] = p;
    }
    __syncthreads();

    int wave = threadIdx.x >> 6;
    int lane = threadIdx.x & 63;
    int slot = lane / 5;            // 0..12 (12 = idle lanes 60..63)
    int l    = lane - slot * 5;     // half2 index within the row
    float* pb = part + (size_t)blockIdx.x * TILE;
    const __half2* h2 = (const __half2*)h;

    if (slot < 12) {
        int g = wave * 12 + slot;   // 0..95
        for (int loc = g; loc < BSIZE; loc += 96) {
            int e0 = loc ? cur[loc - 1] : 0;
            int e1 = cur[loc];
            float ax0 = 0.f, ay0 = 0.f, ax1 = 0.f, ay1 = 0.f;
            float ax2 = 0.f, ay2 = 0.f, ax3 = 0.f, ay3 = 0.f;
            int e = e0;
            for (; e + 7 < e1; e += 8) {
                float2 v0 = __half22float2(h2[(size_t)(srt[e]     & 0x1FFFF) * 5 + l]);
                float2 v1 = __half22float2(h2[(size_t)(srt[e + 1] & 0x1FFFF) * 5 + l]);
                float2 v2 = __half22float2(h2[(size_t)(srt[e + 2] & 0x1FFFF) * 5 + l]);
                float2 v3 = __half22float2(h2[(size_t)(srt[e + 3] & 0x1FFFF) * 5 + l]);
                float2 v4 = __half22float2(h2[(size_t)(srt[e + 4] & 0x1FFFF) * 5 + l]);
                float2 v5 = __half22float2(h2[(size_t)(srt[e + 5] & 0x1FFFF) * 5 + l]);
                float2 v6 = __half22float2(h2[(size_t)(srt[e + 6] & 0x1FFFF) * 5 + l]);
                float2 v7 = __half22float2(h2[(size_t)(srt[e + 7] & 0x1FFFF) * 5 + l]);
                ax0 += v0.x + v4.x; ay0 += v0.y + v4.y;
                ax1 += v1.x + v5.x; ay1 += v1.y + v5.y;
                ax2 += v2.x + v6.x; ay2 += v2.y + v6.y;
                ax3 += v3.x + v7.x; ay3 += v3.y + v7.y;
            }
            for (; e < e1; ++e) {
                float2 v = __half22float2(h2[(size_t)(srt[e] & 0x1FFFF) * 5 + l]);
                ax0 += v.x; ay0 += v.y;
            }
            pb[loc * DIM + 2 * l]     = (ax0 + ax1) + (ax2 + ax3);
            pb[loc * DIM + 2 * l + 1] = (ay0 + ay1) + (ay2 + ay3);
        }
    }
    __syncthreads();

    // overflow fallback (statistically never; correctness guard)
    for (int i = CAP + threadIdx.x; i < n; i += 512) {
        int p = pk[c0 + i];
        int loc = p >> 17, s = p & 0x1FFFF;
#pragma unroll
        for (int j = 0; j < 5; ++j) {
            float2 v = __half22float2(h2[(size_t)s * 5 + j]);
            atomicAdd(&pb[loc * DIM + 2 * j], v.x);
            atomicAdd(&pb[loc * DIM + 2 * j + 1], v.y);
        }
    }
}

// merge CHUNKS partials + fused relu -> r (fp16, compact stride 10)
__global__ __launch_bounds__(256) void k_merge_relu(const float* __restrict__ part,
                                                    __half* __restrict__ r) {
    int b     = blockIdx.x;
    int nbase = b << BSHIFT;
    const float* p0 = part + (size_t)(b * CHUNKS) * TILE;
    __half2* r2 = (__half2*)r;
    for (int t = threadIdx.x; t < TILE / 2; t += 256) {
        float sx = 0.f, sy = 0.f;
#pragma unroll
        for (int c = 0; c < CHUNKS; ++c) {
            float2 v = ((const float2*)(p0 + (size_t)c * TILE))[t];
            sx += v.x; sy += v.y;
        }
        int ebase = nbase * DIM + 2 * t;
        if (ebase < N_NODES * DIM)
            r2[(size_t)nbase * 5 + t] = __floats2half2_rn(fmaxf(sx, 0.f), fmaxf(sy, 0.f));
    }
}

// ---------------------------------------------------------------------------
// Pass 2 v5: bucket spans <=1 graph boundary in ~all cases. Branchless dual
// accumulator (loc < cut selects graph A vs B; cut=256 for uniform buckets),
// 8-deep batched pk->r loads, direct global-atomic flush of <=2 graph rows.
// Generic path (span>=2, ultra-rare) does per-edge cut counting.
// ---------------------------------------------------------------------------
__global__ __launch_bounds__(512) void k_pass2(const __half* __restrict__ r,
                                               const int* __restrict__ bstart,
                                               const int* __restrict__ pk,
                                               const int* __restrict__ bound,
                                               float* __restrict__ sums) {
    __shared__ float acc[NUM_GRAPHS * ACC_STRIDE];

    int b     = blockIdx.x / PCHUNKS;
    int chunk = blockIdx.x % PCHUNKS;
    int nbase = b << BSHIFT;
    int nlast = min(nbase + BSIZE - 1, N_NODES - 1);

    // graph span of this bucket (wave-uniform; bound is L1/L2-hot)
    int glo = 0, ghx = NUM_GRAPHS - 1;
#pragma unroll
    for (int it = 0; it < 6; ++it) {
        int mid = (glo + ghx + 1) >> 1;
        if (bound[mid] <= nbase) glo = mid; else ghx = mid - 1;
    }
    int lo2 = 0, hi2 = NUM_GRAPHS - 1;
#pragma unroll
    for (int it = 0; it < 6; ++it) {
        int mid = (lo2 + hi2 + 1) >> 1;
        if (bound[mid] <= nlast) lo2 = mid; else hi2 = mid - 1;
    }
    int ghi  = lo2;
    int span = ghi - glo;

    for (int t = threadIdx.x; t < (span + 1) * DIM; t += 512)
        acc[(glo + t / DIM) * ACC_STRIDE + t % DIM] = 0.f;
    __syncthreads();

    int s0  = bstart[b];
    int len = bstart[b + 1] - s0;
    int c0  = s0 + (len * chunk) / PCHUNKS;
    int c1  = s0 + (len * (chunk + 1)) / PCHUNKS;

    int wave = threadIdx.x >> 6;
    int lane = threadIdx.x & 63;
    int slot = lane / 5;
    int l    = lane - slot * 5;
    const __half2* r2 = (const __half2*)r;

    if (slot < 12) {
        const int STR = 96;
        int q = wave * 12 + slot;
        int e = c0 + q;
        if (span <= 1) {
            int gA  = glo;
            int gB  = (span == 1) ? glo + 1 : glo;
            int cut = (span == 1) ? (bound[glo + 1] - nbase) : BSIZE;
            float axA = 0.f, ayA = 0.f, axB = 0.f, ayB = 0.f;
            for (; e + 7 * STR < c1; e += 8 * STR) {
                int p[8];
#pragma unroll
                for (int u = 0; u < 8; ++u) p[u] = pk[e + u * STR];
                float2 v[8];
#pragma unroll
                for (int u = 0; u < 8; ++u)
                    v[u] = __half22float2(r2[(size_t)(p[u] & 0x1FFFF) * 5 + l]);
#pragma unroll
                for (int u = 0; u < 8; ++u) {
                    bool a = (p[u] >> 17) < cut;
                    axA += a ? v[u].x : 0.f;  ayA += a ? v[u].y : 0.f;
                    axB += a ? 0.f : v[u].x;  ayB += a ? 0.f : v[u].y;
                }
            }
            for (; e < c1; e += STR) {
                int p = pk[e];
                float2 v = __half22float2(r2[(size_t)(p & 0x1FFFF) * 5 + l]);
                bool a = (p >> 17) < cut;
                axA += a ? v.x : 0.f;  ayA += a ? v.y : 0.f;
                axB += a ? 0.f : v.x;  ayB += a ? 0.f : v.y;
            }
            atomicAdd(&acc[gA * ACC_STRIDE + 2 * l], axA);
            atomicAdd(&acc[gA * ACC_STRIDE + 2 * l + 1], ayA);
            if (span == 1) {
                atomicAdd(&acc[gB * ACC_STRIDE + 2 * l], axB);
                atomicAdd(&acc[gB * ACC_STRIDE + 2 * l + 1], ayB);
            }
        } else {
            // generic (rare): per-edge graph via cut counting
            for (; e < c1; e += STR) {
                int p   = pk[e];
                int loc = p >> 17;
                float2 v = __half22float2(r2[(size_t)(p & 0x1FFFF) * 5 + l]);
                int g = glo;
                for (int gg = glo + 1; gg <= ghi; ++gg)
                    g += (loc >= bound[gg] - nbase) ? 1 : 0;
                atomicAdd(&acc[g * ACC_STRIDE + 2 * l], v.x);
                atomicAdd(&acc[g * ACC_STRIDE + 2 * l + 1], v.y);
            }
        }
    }
    __syncthreads();

    for (int t = threadIdx.x; t < (span + 1) * DIM; t += 512) {
        int g = glo + t / DIM;
        float v = acc[g * ACC_STRIDE + t % DIM];
        if (v != 0.f) atomicAdd(&sums[g * DIM + t % DIM], v);
    }
}

// out[g] = sigmoid(((sums[g]/max(cnt,1)) @ W2) @ W3)
__global__ void k_final(const float* __restrict__ sums, const int* __restrict__ bound,
                        const float* __restrict__ W2, const float* __restrict__ W3,
                        float* __restrict__ out) {
    int g = threadIdx.x;
    if (g >= NUM_GRAPHS) return;
    float c = fmaxf((float)(bound[g + 1] - bound[g]), 1.f);
    float p[DIM];
#pragma unroll
    for (int k = 0; k < DIM; ++k) p[k] = sums[g * DIM + k] / c;
    float z = 0.f;
#pragma unroll
    for (int j = 0; j < DIM; ++j) {
        float t = 0.f;
#pragma unroll
        for (int k = 0; k < DIM; ++k) t += p[k] * W2[k * DIM + j];
        z += t * W3[j];
    }
    out[g] = 1.f / (1.f + expf(-z));
}

// ---------------------------------------------------------------------------
// Workspace (bytes):
//   h1     [0,         2000000)   100k x 10 fp16 (L2-resident)
//   pk     [2000000,  14800000)   3.2M int, dst-bucket-sorted (both passes)
//   r      [14800000, 16800000)   100k x 10 fp16 (L2-resident)
//   part   [16800000, 24807680)   782 x 2560 f32
//   H      [24807680, 25208064)   256 x 391 int
//   tot    [25208064, 25209628)   391 int
//   base   [25209632, 25211196)   391 int
//   bstart [25211200, 25212768)   392 int
//   bound  [25212768, 25213028)   65 int
//   sums   [25213028, 25215588)   640 f32  (zeroed by k_scan2)
// ---------------------------------------------------------------------------
extern "C" void kernel_launch(void* const* d_in, const int* in_sizes, int n_in,
                              void* d_out, int out_size, void* d_ws, size_t ws_size,
                              hipStream_t stream) {
    const float* feat = (const float*)d_in[0];
    const float* W1   = (const float*)d_in[1];
    const float* W2   = (const float*)d_in[2];
    const float* W3   = (const float*)d_in[3];
    const int*   src  = (const int*)d_in[4];
    const int*   dst  = (const int*)d_in[5];
    const int*   gids = (const int*)d_in[6];
    float*       out  = (float*)d_out;

    char* ws = (char*)d_ws;
    __half* h1     = (__half*)(ws);
    int*    pk     = (int*)(ws + 2000000);
    __half* r      = (__half*)(ws + 14800000);
    float*  part   = (float*)(ws + 16800000);
    int*    H      = (int*)(ws + 24807680);
    int*    tot    = (int*)(ws + 25208064);
    int*    base   = (int*)(ws + 25209632);
    int*    bstart = (int*)(ws + 25211200);
    int*    bound  = (int*)(ws + 25212768);
    float*  sums   = (float*)(ws + 25213028);

    k_gemm_w1<<<(N_NODES * 32 + 255) / 256, 256, 0, stream>>>(feat, W1, h1, gids, bound);
    k_hist   <<<EBLOCKS, 512, 0, stream>>>(dst, H);
    k_scan1  <<<NB, 256, 0, stream>>>(H, tot);
    k_scan2  <<<1, 704, 0, stream>>>(tot, base, bstart, sums);
    k_bplace <<<EBLOCKS, 512, 0, stream>>>(src, dst, H, base, pk);

    k_spmm1     <<<NCHUNK, 512, 0, stream>>>(h1, bstart, pk, part);
    k_merge_relu<<<NB, 256, 0, stream>>>(part, r);
    k_pass2     <<<NCHUNK2, 512, 0, stream>>>(r, bstart, pk, bound, sums);

    k_final<<<1, 64, 0, stream>>>(sums, bound, W2, W3, out);
}